// Round 10
// baseline (228.110 us; speedup 1.0000x reference)
//
#include <hip/hip_runtime.h>
#include <hip/hip_bf16.h>
#include <math.h>

#define N_NODES 50000
#define N_EDGES 400000
#define HEADS   4
#define HC      512
#define IN_DIM  5
#define M_SEL   25000
#define NEG_SLOPE 0.2f

typedef __attribute__((ext_vector_type(8))) short bf16x8;
typedef __attribute__((ext_vector_type(4))) float f32x4;

__device__ inline unsigned short f2bf(float f) {
    union { float f; unsigned u; } v; v.f = f;
    unsigned r = v.u + 0x7FFF + ((v.u >> 16) & 1);   // RNE
    return (unsigned short)(r >> 16);
}
__device__ inline float bf2f(unsigned short b) {
    union { unsigned u; float f; } v; v.u = ((unsigned)b) << 16;
    return v.f;
}

// ---------------------------------------------------------------------------
// Kernel 1: h = x @ W.T (bf16); a_src/a_dst einsum [N,4] f32; deg init to 1.
// ---------------------------------------------------------------------------
#define TR_NPW 8

__global__ __launch_bounds__(256) void k_transform(
        const float* __restrict__ x, const float* __restrict__ W,
        const float* __restrict__ att_src, const float* __restrict__ att_dst,
        unsigned short* __restrict__ h, float* __restrict__ a_src,
        float* __restrict__ a_dst, int* __restrict__ deg) {
    int wave = threadIdx.x >> 6, lane = threadIdx.x & 63;
    int c0 = lane * 8;

    float wreg[40];
    const float4* wp = (const float4*)(W + c0 * IN_DIM);
#pragma unroll
    for (int i = 0; i < 10; i++) ((float4*)wreg)[i] = wp[i];
    float sas[8], sad[8];
    *(float4*)&sas[0] = *(const float4*)(att_src + c0);
    *(float4*)&sas[4] = *(const float4*)(att_src + c0 + 4);
    *(float4*)&sad[0] = *(const float4*)(att_dst + c0);
    *(float4*)&sad[4] = *(const float4*)(att_dst + c0 + 4);

    int n0 = (blockIdx.x * 4 + wave) * TR_NPW;
#pragma unroll
    for (int t = 0; t < TR_NPW; t++) {
        int n = n0 + t;
        if (n >= N_NODES) return;
        float xv[IN_DIM];
#pragma unroll
        for (int i = 0; i < IN_DIM; i++) xv[i] = x[n * IN_DIM + i];

        float ps = 0.f, pd = 0.f;
        bf16x8 hv8;
#pragma unroll
        for (int j = 0; j < 8; j++) {
            float acc = 0.f;
#pragma unroll
            for (int i = 0; i < IN_DIM; i++) acc += xv[i] * wreg[j * IN_DIM + i];
            hv8[j] = (short)f2bf(acc);
            ps += acc * sas[j];
            pd += acc * sad[j];
        }
        *(bf16x8*)(h + (size_t)n * HC + c0) = hv8;

#pragma unroll
        for (int off = 8; off >= 1; off >>= 1) {
            ps += __shfl_xor(ps, off);
            pd += __shfl_xor(pd, off);
        }
        if ((lane & 15) == 0) {
            int head = lane >> 4;
            a_src[n * HEADS + head] = ps;
            a_dst[n * HEADS + head] = pd;
        }
        if (lane == 0) deg[n] = 1;   // self-loop base for histogram
    }
}

// ---------------------------------------------------------------------------
// CSR build (multi-block; R4 lesson: never single-block the scan)
// ---------------------------------------------------------------------------
__global__ void k_hist(const int* __restrict__ ei, int* __restrict__ deg) {
    int e = blockIdx.x * 256 + threadIdx.x;
    if (e < N_EDGES) atomicAdd(&deg[ei[N_EDGES + e]], 1);
}

#define NSCAN_BLK 196

__global__ void k_scan1(const int* __restrict__ deg, int* __restrict__ excl,
                        int* __restrict__ bsum) {
    __shared__ int s[256];
    int i = blockIdx.x * 256 + threadIdx.x;
    int v = (i < N_NODES) ? deg[i] : 0;
    s[threadIdx.x] = v;
    __syncthreads();
    for (int off = 1; off < 256; off <<= 1) {
        int t = (threadIdx.x >= off) ? s[threadIdx.x - off] : 0;
        __syncthreads();
        s[threadIdx.x] += t;
        __syncthreads();
    }
    if (i < N_NODES) excl[i] = s[threadIdx.x] - v;
    if (threadIdx.x == 255) bsum[blockIdx.x] = s[255];
}

__global__ void k_scan3fill(const int* __restrict__ excl, const int* __restrict__ bsum,
                            int* __restrict__ offs, int* __restrict__ curs,
                            int* __restrict__ csr) {
    __shared__ int part[256];
    int tid = threadIdx.x;
    part[tid] = (tid < NSCAN_BLK) ? bsum[tid] : 0;
    __syncthreads();
    for (int off = 1; off < 256; off <<= 1) {
        int t = (tid >= off) ? part[tid - off] : 0;
        __syncthreads();
        part[tid] += t;
        __syncthreads();
    }
    int blockoff = (blockIdx.x == 0) ? 0 : part[blockIdx.x - 1];
    int i = blockIdx.x * 256 + tid;
    if (i < N_NODES) {
        int o = excl[i] + blockoff;
        offs[i] = o;
        csr[o] = i;          // self loop in slot 0
        curs[i] = o + 1;
    }
}

__global__ void k_fill_edges(const int* __restrict__ ei, int* __restrict__ cursor,
                             int* __restrict__ csr) {
    int e = blockIdx.x * 256 + threadIdx.x;
    if (e < N_EDGES) {
        int d = ei[N_EDGES + e];
        int pos = atomicAdd(&cursor[d], 1);
        csr[pos] = ei[e];
    }
}

// ---------------------------------------------------------------------------
// Aggregate — TEAM NODES ONLY, one wave per dst node.
// Fast path (dn<=16): the 16 row gathers are ASM VOLATILE global_load_dwordx4
// (opaque to the scheduler — cannot be sunk; R6-R9: every compiler-visible
// form was serialized to ~3 loads in flight, VGPR 44-48). All 16 issue
// back-to-back (16KB in flight/wave), softmax DS/VALU chain runs under them,
// consume uses counted s_waitcnt vmcnt(15-e) TIED to the register (rule #18:
// untied wait asm does not order register readers).
// ---------------------------------------------------------------------------
__global__ __launch_bounds__(256, 4) void k_aggregate(
        const unsigned short* __restrict__ h, const float* __restrict__ a_src,
        const float* __restrict__ a_dst, const int* __restrict__ csr,
        const int* __restrict__ offs, const int* __restrict__ deg,
        const float* __restrict__ bias, unsigned short* __restrict__ emb_sel) {
    int wave = threadIdx.x >> 6, lane = threadIdx.x & 63;
    int w = blockIdx.x * 4 + wave;           // grid exact: w < M_SEL always
    int n = ((w >> 2) << 3) + (w & 3);       // TEAM_IDX[w]

    int base = offs[n];
    int dn = deg[n];
    int head = lane >> 4, egrp = lane & 15;
    int c0 = lane * 8;

    float acc[8];
#pragma unroll
    for (int j = 0; j < 8; j++) acc[j] = -INFINITY;

    if (dn <= 16) {
        // softmax scalar chain first (its compiler-inserted waits must not
        // drain the asm gathers, so consume araw BEFORE issuing them)
        int slot = (egrp < dn) ? egrp : (dn - 1);
        int s_e = csr[base + slot];
        float adn = a_dst[n * HEADS + head];
        float araw = a_src[s_e * HEADS + head];
        float tl = araw + adn;
        tl = (tl > 0.f) ? tl : NEG_SLOPE * tl;
        if (egrp >= dn) tl = -INFINITY;

        // 16 batched gathers — asm volatile, issue pinned here
        bf16x8 v[16];
#pragma unroll
        for (int e = 0; e < 16; e++) {
            int s = __shfl(s_e, e);
            const unsigned short* ap = h + (size_t)s * HC + c0;
            asm volatile("global_load_dwordx4 %0, %1, off"
                         : "=v"(v[e]) : "v"(ap) : "memory");
        }

        // softmax (DS/VALU only — overlaps the 16 loads)
        float m = tl;
#pragma unroll
        for (int off = 8; off >= 1; off >>= 1) m = fmaxf(m, __shfl_xor(m, off));
        float ex = (egrp < dn) ? __expf(tl - m) : 0.f;
        float den = ex;
#pragma unroll
        for (int off = 8; off >= 1; off >>= 1) den += __shfl_xor(den, off);
        float attn = ex / den;

        // consume oldest-first with counted waits (never drain to 0 early)
#pragma unroll
        for (int e = 0; e < 16; e++) {
            asm volatile("s_waitcnt vmcnt(%1)" : "+v"(v[e]) : "i"(15 - e));
            int ei = (e < dn) ? e : (dn - 1);      // dup replays edge dn-1:
            float a = __shfl(attn, (head << 4) | ei);  // idempotent under fmax
#pragma unroll
            for (int j = 0; j < 8; j++)
                acc[j] = fmaxf(acc[j], bf2f((unsigned short)v[e][j]) * a);
        }
    } else {
        // fallback: 3-pass (rare, dn>16)
        float adn = a_dst[n * HEADS + head];
        float m = -INFINITY;
        for (int e0 = 0; e0 < dn; e0 += 16) {
            int e = e0 + egrp;
            if (e < dn) {
                int s = csr[base + e];
                float t = a_src[s * HEADS + head] + adn;
                t = (t > 0.f) ? t : NEG_SLOPE * t;
                m = fmaxf(m, t);
            }
        }
#pragma unroll
        for (int off = 8; off >= 1; off >>= 1) m = fmaxf(m, __shfl_xor(m, off));
        float den = 0.f;
        for (int e0 = 0; e0 < dn; e0 += 16) {
            int e = e0 + egrp;
            if (e < dn) {
                int s = csr[base + e];
                float t = a_src[s * HEADS + head] + adn;
                t = (t > 0.f) ? t : NEG_SLOPE * t;
                den += __expf(t - m);
            }
        }
#pragma unroll
        for (int off = 8; off >= 1; off >>= 1) den += __shfl_xor(den, off);
        float invden = 1.0f / den;
        for (int e = 0; e < dn; e++) {
            int s = csr[base + e];
            float t = a_src[s * HEADS + head] + adn;
            t = (t > 0.f) ? t : NEG_SLOPE * t;
            float attn = __expf(t - m) * invden;
            bf16x8 hv = *(const bf16x8*)(h + (size_t)s * HC + c0);
#pragma unroll
            for (int j = 0; j < 8; j++)
                acc[j] = fmaxf(acc[j], bf2f((unsigned short)hv[j]) * attn);
        }
    }

    bf16x8 ov;
#pragma unroll
    for (int j = 0; j < 8; j++) ov[j] = (short)f2bf(acc[j] + bias[c0 + j]);
    *(bf16x8*)(emb_sel + (size_t)w * HC + c0) = ov;
}

// ---------------------------------------------------------------------------
// bf16 MFMA GEMM:  acc = A @ Wt^T + bias (relu).
// 128x128 tile, BK=64, 256 threads (2x2 waves, 64x64/wave) — R9 lesson:
// 256^2 tile gave grid 196 < 256 CUs (14% occupancy, MfmaUtil 9%).
// Grid now (4,196)=784 blocks, ~3/CU. Staging is branch-free (OOB A rows
// read adjacent allocated ws regions; stores remain guarded by m<M).
// MODE 0: store relu(acc) bf16. MODE 1: fused final layer (dot with W3,
// shuffle reduce, f32 atomic partials — h2 never materialized).
// ---------------------------------------------------------------------------
#define BK  64
#define LDK 72

__device__ inline bf16x8 cvt8(float4 a, float4 b) {
    bf16x8 r;
    r[0] = (short)f2bf(a.x); r[1] = (short)f2bf(a.y);
    r[2] = (short)f2bf(a.z); r[3] = (short)f2bf(a.w);
    r[4] = (short)f2bf(b.x); r[5] = (short)f2bf(b.y);
    r[6] = (short)f2bf(b.z); r[7] = (short)f2bf(b.w);
    return r;
}

template <int MODE>
__global__ __launch_bounds__(256, 3) void k_gemm(const unsigned short* __restrict__ A, int M,
                                                 const float* __restrict__ Wt,
                                                 const float* __restrict__ bias,
                                                 unsigned short* __restrict__ C,
                                                 const float* __restrict__ W3,
                                                 float* __restrict__ part) {
    __shared__ unsigned short As[128 * LDK];
    __shared__ unsigned short Bs[128 * LDK];
    int tid = threadIdx.x;
    int m0 = blockIdx.y * 128;
    int o0 = blockIdx.x * 128;
    int wv = tid >> 6, lane = tid & 63;
    int wm = wv >> 1, wn = wv & 1;   // 2 x 2 wave grid

    f32x4 acc[4][4];
#pragma unroll
    for (int i = 0; i < 4; i++)
#pragma unroll
        for (int j = 0; j < 4; j++) acc[i][j] = (f32x4){0.f, 0.f, 0.f, 0.f};

    bf16x8 ra[4], rb[4];
#pragma unroll
    for (int s = 0; s < 4; s++) {
        int c = s * 256 + tid;           // 0..1023
        int row = c >> 3, col = (c & 7) * 8;
        ra[s] = *(const bf16x8*)(A + (size_t)(m0 + row) * HC + col);
        const float4* wp = (const float4*)(Wt + (size_t)(o0 + row) * HC + col);
        rb[s] = cvt8(wp[0], wp[1]);
    }

    for (int k0 = 0; k0 < HC; k0 += BK) {
        __syncthreads();
#pragma unroll
        for (int s = 0; s < 4; s++) {
            int c = s * 256 + tid;
            int row = c >> 3, col = (c & 7) * 8;
            *(bf16x8*)(&As[row * LDK + col]) = ra[s];
            *(bf16x8*)(&Bs[row * LDK + col]) = rb[s];
        }
        __syncthreads();

        int kn = k0 + BK;
        if (kn < HC) {
#pragma unroll
            for (int s = 0; s < 4; s++) {
                int c = s * 256 + tid;
                int row = c >> 3, col = (c & 7) * 8;
                ra[s] = *(const bf16x8*)(A + (size_t)(m0 + row) * HC + kn + col);
                const float4* wp = (const float4*)(Wt + (size_t)(o0 + row) * HC + kn + col);
                rb[s] = cvt8(wp[0], wp[1]);
            }
        }

#pragma unroll
        for (int kk = 0; kk < 2; kk++) {
            int kb = kk * 32 + (lane >> 4) * 8;
            bf16x8 af[4], bfr[4];
#pragma unroll
            for (int mi = 0; mi < 4; mi++)
                af[mi] = *(const bf16x8*)(&As[(wm * 64 + mi * 16 + (lane & 15)) * LDK + kb]);
#pragma unroll
            for (int ni = 0; ni < 4; ni++)
                bfr[ni] = *(const bf16x8*)(&Bs[(wn * 64 + ni * 16 + (lane & 15)) * LDK + kb]);
#pragma unroll
            for (int mi = 0; mi < 4; mi++)
#pragma unroll
                for (int ni = 0; ni < 4; ni++)
                    acc[mi][ni] = __builtin_amdgcn_mfma_f32_16x16x32_bf16(
                        af[mi], bfr[ni], acc[mi][ni], 0, 0, 0);
        }
    }

    if (MODE == 0) {
#pragma unroll
        for (int ni = 0; ni < 4; ni++) {
            int ncol = o0 + wn * 64 + ni * 16 + (lane & 15);
            float bv = bias[ncol];
#pragma unroll
            for (int mi = 0; mi < 4; mi++) {
                int mbase = m0 + wm * 64 + mi * 16 + (lane >> 4) * 4;
#pragma unroll
                for (int r = 0; r < 4; r++) {
                    int m = mbase + r;
                    if (m < M) {
                        float v = fmaxf(acc[mi][ni][r] + bv, 0.f);
                        C[(size_t)m * HC + ncol] = f2bf(v);
                    }
                }
            }
        }
    } else {
        float p0[4][4], p1[4][4];
#pragma unroll
        for (int mi = 0; mi < 4; mi++)
#pragma unroll
            for (int r = 0; r < 4; r++) { p0[mi][r] = 0.f; p1[mi][r] = 0.f; }
#pragma unroll
        for (int ni = 0; ni < 4; ni++) {
            int ncol = o0 + wn * 64 + ni * 16 + (lane & 15);
            float bv = bias[ncol];
            float w0 = W3[ncol], w1 = W3[HC + ncol];
#pragma unroll
            for (int mi = 0; mi < 4; mi++)
#pragma unroll
                for (int r = 0; r < 4; r++) {
                    float v = fmaxf(acc[mi][ni][r] + bv, 0.f);
                    p0[mi][r] += v * w0;
                    p1[mi][r] += v * w1;
                }
        }
#pragma unroll
        for (int mi = 0; mi < 4; mi++)
#pragma unroll
            for (int r = 0; r < 4; r++) {
                float a0 = p0[mi][r], a1 = p1[mi][r];
#pragma unroll
                for (int off = 8; off >= 1; off >>= 1) {
                    a0 += __shfl_xor(a0, off);
                    a1 += __shfl_xor(a1, off);
                }
                int m = m0 + wm * 64 + mi * 16 + (lane >> 4) * 4 + r;
                if ((lane & 15) == 0 && m < M) {
                    atomicAdd(&part[m * 2 + 0], a0);
                    atomicAdd(&part[m * 2 + 1], a1);
                }
            }
    }
}

// ---------------------------------------------------------------------------
// out[i] = tanh(part[i] + b3[i&1])
// ---------------------------------------------------------------------------
__global__ void k_tanh(const float* __restrict__ part, const float* __restrict__ b3,
                       float* __restrict__ out) {
    int i = blockIdx.x * 256 + threadIdx.x;
    if (i < 2 * M_SEL) out[i] = tanhf(part[i] + b3[i & 1]);
}

// ---------------------------------------------------------------------------
extern "C" void kernel_launch(void* const* d_in, const int* in_sizes, int n_in,
                              void* d_out, int out_size, void* d_ws, size_t ws_size,
                              hipStream_t stream) {
    const float* x       = (const float*)d_in[0];
    const int*   ei      = (const int*)d_in[1];
    const float* W       = (const float*)d_in[3];
    const float* att_src = (const float*)d_in[4];
    const float* att_dst = (const float*)d_in[5];
    const float* bias    = (const float*)d_in[6];
    const float* W1      = (const float*)d_in[7];
    const float* b1      = (const float*)d_in[8];
    const float* W2      = (const float*)d_in[9];
    const float* b2      = (const float*)d_in[10];
    const float* W3      = (const float*)d_in[11];
    const float* b3      = (const float*)d_in[12];
    float* out = (float*)d_out;

    char* ws = (char*)d_ws;
    unsigned short* h       = (unsigned short*)(ws);               // 51,200,000
    unsigned short* emb_sel = (unsigned short*)(ws + 51200000);    // 25,600,000
    unsigned short* h1      = (unsigned short*)(ws + 76800000);    // 25,600,000
    float* part  = (float*)(ws + 102400000);                       //    200,000
    float* a_src = (float*)(ws + 129048576);                       //    800,000
    float* a_dst = (float*)(ws + 129848576);                       //    800,000
    int*   deg   = (int*)  (ws + 130648576);                       //    200,000
    int*   offs  = (int*)  (ws + 130848576);                       //    200,000
    int*   curs  = (int*)  (ws + 131048576);                       //    200,000
    int*   excl  = (int*)  (ws + 131248576);                       //    200,000
    int*   bsum  = (int*)  (ws + 131448576);                       //      1,024
    int*   csr   = (int*)  (ws + 131449600);                       //  1,800,000  (~133 MB)

    hipMemsetAsync(part, 0, 2 * M_SEL * sizeof(float), stream);
    k_transform<<<(N_NODES + 31) / 32, 256, 0, stream>>>(x, W, att_src, att_dst, h,
                                                         a_src, a_dst, deg);
    k_hist<<<(N_EDGES + 255) / 256, 256, 0, stream>>>(ei, deg);
    k_scan1<<<NSCAN_BLK, 256, 0, stream>>>(deg, excl, bsum);
    k_scan3fill<<<NSCAN_BLK, 256, 0, stream>>>(excl, bsum, offs, curs, csr);
    k_fill_edges<<<(N_EDGES + 255) / 256, 256, 0, stream>>>(ei, curs, csr);
    k_aggregate<<<6250, 256, 0, stream>>>(h, a_src, a_dst, csr, offs, deg, bias, emb_sel);

    dim3 g(4, 196);
    k_gemm<0><<<g, 256, 0, stream>>>(emb_sel, M_SEL, W1, b1, h1, nullptr, nullptr);
    k_gemm<1><<<g, 256, 0, stream>>>(h1, M_SEL, W2, b2, nullptr, W3, part);
    k_tanh<<<196, 256, 0, stream>>>(part, b3, out);
}

// Round 11
// 211.573 us; speedup vs baseline: 1.0782x; 1.0782x over previous
//
#include <hip/hip_runtime.h>
#include <hip/hip_bf16.h>
#include <math.h>

#define N_NODES 50000
#define N_EDGES 400000
#define HEADS   4
#define HC      512
#define IN_DIM  5
#define M_SEL   25000
#define NEG_SLOPE 0.2f

typedef __attribute__((ext_vector_type(8))) short bf16x8;
typedef __attribute__((ext_vector_type(4))) float f32x4;

__device__ inline unsigned short f2bf(float f) {
    union { float f; unsigned u; } v; v.f = f;
    unsigned r = v.u + 0x7FFF + ((v.u >> 16) & 1);   // RNE
    return (unsigned short)(r >> 16);
}
__device__ inline float bf2f(unsigned short b) {
    union { unsigned u; float f; } v; v.u = ((unsigned)b) << 16;
    return v.f;
}

// ---------------------------------------------------------------------------
// Kernel 1: h = x @ W.T (bf16); a_src/a_dst einsum [N,4] f32; deg init to 1.
// ---------------------------------------------------------------------------
#define TR_NPW 8

__global__ __launch_bounds__(256) void k_transform(
        const float* __restrict__ x, const float* __restrict__ W,
        const float* __restrict__ att_src, const float* __restrict__ att_dst,
        unsigned short* __restrict__ h, float* __restrict__ a_src,
        float* __restrict__ a_dst, int* __restrict__ deg) {
    int wave = threadIdx.x >> 6, lane = threadIdx.x & 63;
    int c0 = lane * 8;

    float wreg[40];
    const float4* wp = (const float4*)(W + c0 * IN_DIM);
#pragma unroll
    for (int i = 0; i < 10; i++) ((float4*)wreg)[i] = wp[i];
    float sas[8], sad[8];
    *(float4*)&sas[0] = *(const float4*)(att_src + c0);
    *(float4*)&sas[4] = *(const float4*)(att_src + c0 + 4);
    *(float4*)&sad[0] = *(const float4*)(att_dst + c0);
    *(float4*)&sad[4] = *(const float4*)(att_dst + c0 + 4);

    int n0 = (blockIdx.x * 4 + wave) * TR_NPW;
#pragma unroll
    for (int t = 0; t < TR_NPW; t++) {
        int n = n0 + t;
        if (n >= N_NODES) return;
        float xv[IN_DIM];
#pragma unroll
        for (int i = 0; i < IN_DIM; i++) xv[i] = x[n * IN_DIM + i];

        float ps = 0.f, pd = 0.f;
        bf16x8 hv8;
#pragma unroll
        for (int j = 0; j < 8; j++) {
            float acc = 0.f;
#pragma unroll
            for (int i = 0; i < IN_DIM; i++) acc += xv[i] * wreg[j * IN_DIM + i];
            hv8[j] = (short)f2bf(acc);
            ps += acc * sas[j];
            pd += acc * sad[j];
        }
        *(bf16x8*)(h + (size_t)n * HC + c0) = hv8;

#pragma unroll
        for (int off = 8; off >= 1; off >>= 1) {
            ps += __shfl_xor(ps, off);
            pd += __shfl_xor(pd, off);
        }
        if ((lane & 15) == 0) {
            int head = lane >> 4;
            a_src[n * HEADS + head] = ps;
            a_dst[n * HEADS + head] = pd;
        }
        if (lane == 0) deg[n] = 1;   // self-loop base for histogram
    }
}

// ---------------------------------------------------------------------------
// CSR build (multi-block; R4 lesson: never single-block the scan)
// ---------------------------------------------------------------------------
__global__ void k_hist(const int* __restrict__ ei, int* __restrict__ deg) {
    int e = blockIdx.x * 256 + threadIdx.x;
    if (e < N_EDGES) atomicAdd(&deg[ei[N_EDGES + e]], 1);
}

#define NSCAN_BLK 196

__global__ void k_scan1(const int* __restrict__ deg, int* __restrict__ excl,
                        int* __restrict__ bsum) {
    __shared__ int s[256];
    int i = blockIdx.x * 256 + threadIdx.x;
    int v = (i < N_NODES) ? deg[i] : 0;
    s[threadIdx.x] = v;
    __syncthreads();
    for (int off = 1; off < 256; off <<= 1) {
        int t = (threadIdx.x >= off) ? s[threadIdx.x - off] : 0;
        __syncthreads();
        s[threadIdx.x] += t;
        __syncthreads();
    }
    if (i < N_NODES) excl[i] = s[threadIdx.x] - v;
    if (threadIdx.x == 255) bsum[blockIdx.x] = s[255];
}

__global__ void k_scan3fill(const int* __restrict__ excl, const int* __restrict__ bsum,
                            int* __restrict__ offs, int* __restrict__ curs,
                            int* __restrict__ csr) {
    __shared__ int part[256];
    int tid = threadIdx.x;
    part[tid] = (tid < NSCAN_BLK) ? bsum[tid] : 0;
    __syncthreads();
    for (int off = 1; off < 256; off <<= 1) {
        int t = (tid >= off) ? part[tid - off] : 0;
        __syncthreads();
        part[tid] += t;
        __syncthreads();
    }
    int blockoff = (blockIdx.x == 0) ? 0 : part[blockIdx.x - 1];
    int i = blockIdx.x * 256 + tid;
    if (i < N_NODES) {
        int o = excl[i] + blockoff;
        offs[i] = o;
        csr[o] = i;          // self loop in slot 0
        curs[i] = o + 1;
    }
}

__global__ void k_fill_edges(const int* __restrict__ ei, int* __restrict__ cursor,
                             int* __restrict__ csr) {
    int e = blockIdx.x * 256 + threadIdx.x;
    if (e < N_EDGES) {
        int d = ei[N_EDGES + e];
        int pos = atomicAdd(&cursor[d], 1);
        csr[pos] = ei[e];
    }
}

// ---------------------------------------------------------------------------
// Aggregate — TEAM NODES ONLY, one wave per dst node.
// Fast path (dn<=16): 16 asm-volatile batched gathers (16KB in flight),
// softmax DS/VALU chain under the loads, counted vmcnt consume (R10).
// ---------------------------------------------------------------------------
__global__ __launch_bounds__(256, 4) void k_aggregate(
        const unsigned short* __restrict__ h, const float* __restrict__ a_src,
        const float* __restrict__ a_dst, const int* __restrict__ csr,
        const int* __restrict__ offs, const int* __restrict__ deg,
        const float* __restrict__ bias, unsigned short* __restrict__ emb_sel) {
    int wave = threadIdx.x >> 6, lane = threadIdx.x & 63;
    int w = blockIdx.x * 4 + wave;           // grid exact: w < M_SEL always
    int n = ((w >> 2) << 3) + (w & 3);       // TEAM_IDX[w]

    int base = offs[n];
    int dn = deg[n];
    int head = lane >> 4, egrp = lane & 15;
    int c0 = lane * 8;

    float acc[8];
#pragma unroll
    for (int j = 0; j < 8; j++) acc[j] = -INFINITY;

    if (dn <= 16) {
        int slot = (egrp < dn) ? egrp : (dn - 1);
        int s_e = csr[base + slot];
        float adn = a_dst[n * HEADS + head];
        float araw = a_src[s_e * HEADS + head];
        float tl = araw + adn;
        tl = (tl > 0.f) ? tl : NEG_SLOPE * tl;
        if (egrp >= dn) tl = -INFINITY;

        // 16 batched gathers — asm volatile, issue pinned here
        bf16x8 v[16];
#pragma unroll
        for (int e = 0; e < 16; e++) {
            int s = __shfl(s_e, e);
            const unsigned short* ap = h + (size_t)s * HC + c0;
            asm volatile("global_load_dwordx4 %0, %1, off"
                         : "=v"(v[e]) : "v"(ap) : "memory");
        }

        // softmax (DS/VALU only — overlaps the 16 loads)
        float m = tl;
#pragma unroll
        for (int off = 8; off >= 1; off >>= 1) m = fmaxf(m, __shfl_xor(m, off));
        float ex = (egrp < dn) ? __expf(tl - m) : 0.f;
        float den = ex;
#pragma unroll
        for (int off = 8; off >= 1; off >>= 1) den += __shfl_xor(den, off);
        float attn = ex / den;

        // consume oldest-first with counted waits
#pragma unroll
        for (int e = 0; e < 16; e++) {
            asm volatile("s_waitcnt vmcnt(%1)" : "+v"(v[e]) : "i"(15 - e));
            int ei = (e < dn) ? e : (dn - 1);      // dup replays edge dn-1:
            float a = __shfl(attn, (head << 4) | ei);  // idempotent under fmax
#pragma unroll
            for (int j = 0; j < 8; j++)
                acc[j] = fmaxf(acc[j], bf2f((unsigned short)v[e][j]) * a);
        }
    } else {
        // fallback: 3-pass (rare, dn>16)
        float adn = a_dst[n * HEADS + head];
        float m = -INFINITY;
        for (int e0 = 0; e0 < dn; e0 += 16) {
            int e = e0 + egrp;
            if (e < dn) {
                int s = csr[base + e];
                float t = a_src[s * HEADS + head] + adn;
                t = (t > 0.f) ? t : NEG_SLOPE * t;
                m = fmaxf(m, t);
            }
        }
#pragma unroll
        for (int off = 8; off >= 1; off >>= 1) m = fmaxf(m, __shfl_xor(m, off));
        float den = 0.f;
        for (int e0 = 0; e0 < dn; e0 += 16) {
            int e = e0 + egrp;
            if (e < dn) {
                int s = csr[base + e];
                float t = a_src[s * HEADS + head] + adn;
                t = (t > 0.f) ? t : NEG_SLOPE * t;
                den += __expf(t - m);
            }
        }
#pragma unroll
        for (int off = 8; off >= 1; off >>= 1) den += __shfl_xor(den, off);
        float invden = 1.0f / den;
        for (int e = 0; e < dn; e++) {
            int s = csr[base + e];
            float t = a_src[s * HEADS + head] + adn;
            t = (t > 0.f) ? t : NEG_SLOPE * t;
            float attn = __expf(t - m) * invden;
            bf16x8 hv = *(const bf16x8*)(h + (size_t)s * HC + c0);
#pragma unroll
            for (int j = 0; j < 8; j++)
                acc[j] = fmaxf(acc[j], bf2f((unsigned short)hv[j]) * attn);
        }
    }

    bf16x8 ov;
#pragma unroll
    for (int j = 0; j < 8; j++) ov[j] = (short)f2bf(acc[j] + bias[c0 + j]);
    *(bf16x8*)(emb_sel + (size_t)w * HC + c0) = ov;
}

// ---------------------------------------------------------------------------
// bf16 MFMA GEMM:  acc = A @ Wt^T + bias (relu).
// BM=128 x BN=256, BK=64, 512 threads (8 waves 2m x 4n, 64x64/wave — R9's
// inner loop). Grid (2,196)=392 blocks >= 256 CUs (R10 lesson: 196 blocks
// starved CUs; 784 small blocks quadrupled refetch+sync). LDS 55.3KB ->
// 2 blocks/CU. Staging branch-free (OOB A rows read allocated ws; stores
// guarded). MODE 0: store relu bf16. MODE 1: fused final layer.
// ---------------------------------------------------------------------------
#define BK  64
#define LDK 72

__device__ inline bf16x8 cvt8(float4 a, float4 b) {
    bf16x8 r;
    r[0] = (short)f2bf(a.x); r[1] = (short)f2bf(a.y);
    r[2] = (short)f2bf(a.z); r[3] = (short)f2bf(a.w);
    r[4] = (short)f2bf(b.x); r[5] = (short)f2bf(b.y);
    r[6] = (short)f2bf(b.z); r[7] = (short)f2bf(b.w);
    return r;
}

template <int MODE>
__global__ __launch_bounds__(512, 2) void k_gemm(const unsigned short* __restrict__ A, int M,
                                                 const float* __restrict__ Wt,
                                                 const float* __restrict__ bias,
                                                 unsigned short* __restrict__ C,
                                                 const float* __restrict__ W3,
                                                 float* __restrict__ part) {
    __shared__ unsigned short As[128 * LDK];
    __shared__ unsigned short Bs[256 * LDK];
    int tid = threadIdx.x;
    int m0 = blockIdx.y * 128;
    int o0 = blockIdx.x * 256;
    int wv = tid >> 6, lane = tid & 63;
    int wm = wv >> 2, wn = wv & 3;   // 2 x 4 wave grid

    f32x4 acc[4][4];
#pragma unroll
    for (int i = 0; i < 4; i++)
#pragma unroll
        for (int j = 0; j < 4; j++) acc[i][j] = (f32x4){0.f, 0.f, 0.f, 0.f};

    bf16x8 ra[2], rb[4];
#pragma unroll
    for (int s = 0; s < 2; s++) {
        int c = s * 512 + tid;           // 0..1023  (A: 128 rows x 64 cols)
        int row = c >> 3, col = (c & 7) * 8;
        ra[s] = *(const bf16x8*)(A + (size_t)(m0 + row) * HC + col);
    }
#pragma unroll
    for (int s = 0; s < 4; s++) {
        int c = s * 512 + tid;           // 0..2047  (B: 256 rows x 64 cols)
        int row = c >> 3, col = (c & 7) * 8;
        const float4* wp = (const float4*)(Wt + (size_t)(o0 + row) * HC + col);
        rb[s] = cvt8(wp[0], wp[1]);
    }

    for (int k0 = 0; k0 < HC; k0 += BK) {
        __syncthreads();
#pragma unroll
        for (int s = 0; s < 2; s++) {
            int c = s * 512 + tid;
            int row = c >> 3, col = (c & 7) * 8;
            *(bf16x8*)(&As[row * LDK + col]) = ra[s];
        }
#pragma unroll
        for (int s = 0; s < 4; s++) {
            int c = s * 512 + tid;
            int row = c >> 3, col = (c & 7) * 8;
            *(bf16x8*)(&Bs[row * LDK + col]) = rb[s];
        }
        __syncthreads();

        int kn = k0 + BK;
        if (kn < HC) {
#pragma unroll
            for (int s = 0; s < 2; s++) {
                int c = s * 512 + tid;
                int row = c >> 3, col = (c & 7) * 8;
                ra[s] = *(const bf16x8*)(A + (size_t)(m0 + row) * HC + kn + col);
            }
#pragma unroll
            for (int s = 0; s < 4; s++) {
                int c = s * 512 + tid;
                int row = c >> 3, col = (c & 7) * 8;
                const float4* wp = (const float4*)(Wt + (size_t)(o0 + row) * HC + kn + col);
                rb[s] = cvt8(wp[0], wp[1]);
            }
        }

#pragma unroll
        for (int kk = 0; kk < 2; kk++) {
            int kb = kk * 32 + (lane >> 4) * 8;
            bf16x8 af[4], bfr[4];
#pragma unroll
            for (int mi = 0; mi < 4; mi++)
                af[mi] = *(const bf16x8*)(&As[(wm * 64 + mi * 16 + (lane & 15)) * LDK + kb]);
#pragma unroll
            for (int ni = 0; ni < 4; ni++)
                bfr[ni] = *(const bf16x8*)(&Bs[(wn * 64 + ni * 16 + (lane & 15)) * LDK + kb]);
#pragma unroll
            for (int mi = 0; mi < 4; mi++)
#pragma unroll
                for (int ni = 0; ni < 4; ni++)
                    acc[mi][ni] = __builtin_amdgcn_mfma_f32_16x16x32_bf16(
                        af[mi], bfr[ni], acc[mi][ni], 0, 0, 0);
        }
    }

    if (MODE == 0) {
#pragma unroll
        for (int ni = 0; ni < 4; ni++) {
            int ncol = o0 + wn * 64 + ni * 16 + (lane & 15);
            float bv = bias[ncol];
#pragma unroll
            for (int mi = 0; mi < 4; mi++) {
                int mbase = m0 + wm * 64 + mi * 16 + (lane >> 4) * 4;
#pragma unroll
                for (int r = 0; r < 4; r++) {
                    int m = mbase + r;
                    if (m < M) {
                        float v = fmaxf(acc[mi][ni][r] + bv, 0.f);
                        C[(size_t)m * HC + ncol] = f2bf(v);
                    }
                }
            }
        }
    } else {
        float p0[4][4], p1[4][4];
#pragma unroll
        for (int mi = 0; mi < 4; mi++)
#pragma unroll
            for (int r = 0; r < 4; r++) { p0[mi][r] = 0.f; p1[mi][r] = 0.f; }
#pragma unroll
        for (int ni = 0; ni < 4; ni++) {
            int ncol = o0 + wn * 64 + ni * 16 + (lane & 15);
            float bv = bias[ncol];
            float w0 = W3[ncol], w1 = W3[HC + ncol];
#pragma unroll
            for (int mi = 0; mi < 4; mi++)
#pragma unroll
                for (int r = 0; r < 4; r++) {
                    float v = fmaxf(acc[mi][ni][r] + bv, 0.f);
                    p0[mi][r] += v * w0;
                    p1[mi][r] += v * w1;
                }
        }
#pragma unroll
        for (int mi = 0; mi < 4; mi++)
#pragma unroll
            for (int r = 0; r < 4; r++) {
                float a0 = p0[mi][r], a1 = p1[mi][r];
#pragma unroll
                for (int off = 8; off >= 1; off >>= 1) {
                    a0 += __shfl_xor(a0, off);
                    a1 += __shfl_xor(a1, off);
                }
                int m = m0 + wm * 64 + mi * 16 + (lane >> 4) * 4 + r;
                if ((lane & 15) == 0 && m < M) {
                    atomicAdd(&part[m * 2 + 0], a0);
                    atomicAdd(&part[m * 2 + 1], a1);
                }
            }
    }
}

// ---------------------------------------------------------------------------
// out[i] = tanh(part[i] + b3[i&1])
// ---------------------------------------------------------------------------
__global__ void k_tanh(const float* __restrict__ part, const float* __restrict__ b3,
                       float* __restrict__ out) {
    int i = blockIdx.x * 256 + threadIdx.x;
    if (i < 2 * M_SEL) out[i] = tanhf(part[i] + b3[i & 1]);
}

// ---------------------------------------------------------------------------
extern "C" void kernel_launch(void* const* d_in, const int* in_sizes, int n_in,
                              void* d_out, int out_size, void* d_ws, size_t ws_size,
                              hipStream_t stream) {
    const float* x       = (const float*)d_in[0];
    const int*   ei      = (const int*)d_in[1];
    const float* W       = (const float*)d_in[3];
    const float* att_src = (const float*)d_in[4];
    const float* att_dst = (const float*)d_in[5];
    const float* bias    = (const float*)d_in[6];
    const float* W1      = (const float*)d_in[7];
    const float* b1      = (const float*)d_in[8];
    const float* W2      = (const float*)d_in[9];
    const float* b2      = (const float*)d_in[10];
    const float* W3      = (const float*)d_in[11];
    const float* b3      = (const float*)d_in[12];
    float* out = (float*)d_out;

    char* ws = (char*)d_ws;
    unsigned short* h       = (unsigned short*)(ws);               // 51,200,000
    unsigned short* emb_sel = (unsigned short*)(ws + 51200000);    // 25,600,000
    unsigned short* h1      = (unsigned short*)(ws + 76800000);    // 25,600,000
    float* part  = (float*)(ws + 102400000);                       //    200,000
    float* a_src = (float*)(ws + 129048576);                       //    800,000
    float* a_dst = (float*)(ws + 129848576);                       //    800,000
    int*   deg   = (int*)  (ws + 130648576);                       //    200,000
    int*   offs  = (int*)  (ws + 130848576);                       //    200,000
    int*   curs  = (int*)  (ws + 131048576);                       //    200,000
    int*   excl  = (int*)  (ws + 131248576);                       //    200,000
    int*   bsum  = (int*)  (ws + 131448576);                       //      1,024
    int*   csr   = (int*)  (ws + 131449600);                       //  1,800,000  (~133 MB)

    hipMemsetAsync(part, 0, 2 * M_SEL * sizeof(float), stream);
    k_transform<<<(N_NODES + 31) / 32, 256, 0, stream>>>(x, W, att_src, att_dst, h,
                                                         a_src, a_dst, deg);
    k_hist<<<(N_EDGES + 255) / 256, 256, 0, stream>>>(ei, deg);
    k_scan1<<<NSCAN_BLK, 256, 0, stream>>>(deg, excl, bsum);
    k_scan3fill<<<NSCAN_BLK, 256, 0, stream>>>(excl, bsum, offs, curs, csr);
    k_fill_edges<<<(N_EDGES + 255) / 256, 256, 0, stream>>>(ei, curs, csr);
    k_aggregate<<<6250, 256, 0, stream>>>(h, a_src, a_dst, csr, offs, deg, bias, emb_sel);

    dim3 g(2, 196);
    k_gemm<0><<<g, 512, 0, stream>>>(emb_sel, M_SEL, W1, b1, h1, nullptr, nullptr);
    k_gemm<1><<<g, 512, 0, stream>>>(h1, M_SEL, W2, b2, nullptr, W3, part);
    k_tanh<<<196, 256, 0, stream>>>(part, b3, out);
}

// Round 12
// 198.468 us; speedup vs baseline: 1.1494x; 1.0660x over previous
//
#include <hip/hip_runtime.h>
#include <hip/hip_bf16.h>
#include <math.h>

#define N_NODES 50000
#define N_EDGES 400000
#define HEADS   4
#define HC      512
#define IN_DIM  5
#define M_SEL   25000
#define NEG_SLOPE 0.2f

typedef __attribute__((ext_vector_type(8))) short bf16x8;
typedef __attribute__((ext_vector_type(4))) float f32x4;

__device__ inline unsigned short f2bf(float f) {
    union { float f; unsigned u; } v; v.f = f;
    unsigned r = v.u + 0x7FFF + ((v.u >> 16) & 1);   // RNE
    return (unsigned short)(r >> 16);
}
__device__ inline float bf2f(unsigned short b) {
    union { unsigned u; float f; } v; v.u = ((unsigned)b) << 16;
    return v.f;
}

// ---------------------------------------------------------------------------
// Kernel 1: a_src/a_dst einsum [N,4] f32 + deg init. h is NOT materialized —
// the aggregate recomputes it from x per edge (h store was 51MB of traffic).
// ---------------------------------------------------------------------------
#define TR_NPW 8

__global__ __launch_bounds__(256) void k_transform(
        const float* __restrict__ x, const float* __restrict__ W,
        const float* __restrict__ att_src, const float* __restrict__ att_dst,
        float* __restrict__ a_src, float* __restrict__ a_dst, int* __restrict__ deg) {
    int wave = threadIdx.x >> 6, lane = threadIdx.x & 63;
    int c0 = lane * 8;

    float wreg[40];
    const float4* wp = (const float4*)(W + c0 * IN_DIM);
#pragma unroll
    for (int i = 0; i < 10; i++) ((float4*)wreg)[i] = wp[i];
    float sas[8], sad[8];
    *(float4*)&sas[0] = *(const float4*)(att_src + c0);
    *(float4*)&sas[4] = *(const float4*)(att_src + c0 + 4);
    *(float4*)&sad[0] = *(const float4*)(att_dst + c0);
    *(float4*)&sad[4] = *(const float4*)(att_dst + c0 + 4);

    int n0 = (blockIdx.x * 4 + wave) * TR_NPW;
#pragma unroll
    for (int t = 0; t < TR_NPW; t++) {
        int n = n0 + t;
        if (n >= N_NODES) return;
        float xv[IN_DIM];
#pragma unroll
        for (int i = 0; i < IN_DIM; i++) xv[i] = x[n * IN_DIM + i];

        float ps = 0.f, pd = 0.f;
#pragma unroll
        for (int j = 0; j < 8; j++) {
            float acc = 0.f;
#pragma unroll
            for (int i = 0; i < IN_DIM; i++) acc += xv[i] * wreg[j * IN_DIM + i];
            ps += acc * sas[j];
            pd += acc * sad[j];
        }
#pragma unroll
        for (int off = 8; off >= 1; off >>= 1) {
            ps += __shfl_xor(ps, off);
            pd += __shfl_xor(pd, off);
        }
        if ((lane & 15) == 0) {
            int head = lane >> 4;
            a_src[n * HEADS + head] = ps;
            a_dst[n * HEADS + head] = pd;
        }
        if (lane == 0) deg[n] = 1;   // self-loop base for histogram
    }
}

// ---------------------------------------------------------------------------
// CSR build (multi-block; R4 lesson: never single-block the scan)
// ---------------------------------------------------------------------------
__global__ void k_hist(const int* __restrict__ ei, int* __restrict__ deg) {
    int e = blockIdx.x * 256 + threadIdx.x;
    if (e < N_EDGES) atomicAdd(&deg[ei[N_EDGES + e]], 1);
}

#define NSCAN_BLK 196

__global__ void k_scan1(const int* __restrict__ deg, int* __restrict__ excl,
                        int* __restrict__ bsum) {
    __shared__ int s[256];
    int i = blockIdx.x * 256 + threadIdx.x;
    int v = (i < N_NODES) ? deg[i] : 0;
    s[threadIdx.x] = v;
    __syncthreads();
    for (int off = 1; off < 256; off <<= 1) {
        int t = (threadIdx.x >= off) ? s[threadIdx.x - off] : 0;
        __syncthreads();
        s[threadIdx.x] += t;
        __syncthreads();
    }
    if (i < N_NODES) excl[i] = s[threadIdx.x] - v;
    if (threadIdx.x == 255) bsum[blockIdx.x] = s[255];
}

__global__ void k_scan3fill(const int* __restrict__ excl, const int* __restrict__ bsum,
                            int* __restrict__ offs, int* __restrict__ curs,
                            int* __restrict__ csr) {
    __shared__ int part[256];
    int tid = threadIdx.x;
    part[tid] = (tid < NSCAN_BLK) ? bsum[tid] : 0;
    __syncthreads();
    for (int off = 1; off < 256; off <<= 1) {
        int t = (tid >= off) ? part[tid - off] : 0;
        __syncthreads();
        part[tid] += t;
        __syncthreads();
    }
    int blockoff = (blockIdx.x == 0) ? 0 : part[blockIdx.x - 1];
    int i = blockIdx.x * 256 + tid;
    if (i < N_NODES) {
        int o = excl[i] + blockoff;
        offs[i] = o;
        csr[o] = i;          // self loop in slot 0
        curs[i] = o + 1;
    }
}

__global__ void k_fill_edges(const int* __restrict__ ei, int* __restrict__ cursor,
                             int* __restrict__ csr) {
    int e = blockIdx.x * 256 + threadIdx.x;
    if (e < N_EDGES) {
        int d = ei[N_EDGES + e];
        int pos = atomicAdd(&cursor[d], 1);
        csr[pos] = ei[e];
    }
}

// ---------------------------------------------------------------------------
// Aggregate v2 — TEAM NODES ONLY, one wave per dst node. Instead of gathering
// h[src] (1KB/edge -> 116MB HBM, latency-bound for 4 rounds), RECOMPUTE
// h = x@W.T in-register per edge: broadcast-load x[s] (20B, L1/L2-resident,
// x is 1MB) and 40 FMA per lane. VALU-bound ~11us instead of 47us.
// ---------------------------------------------------------------------------
__global__ __launch_bounds__(256, 4) void k_aggregate(
        const float* __restrict__ x, const float* __restrict__ W,
        const float* __restrict__ a_src, const float* __restrict__ a_dst,
        const int* __restrict__ csr, const int* __restrict__ offs,
        const int* __restrict__ deg, const float* __restrict__ bias,
        unsigned short* __restrict__ emb_sel) {
    int wave = threadIdx.x >> 6, lane = threadIdx.x & 63;
    int w = blockIdx.x * 4 + wave;           // grid exact: w < M_SEL always
    int n = ((w >> 2) << 3) + (w & 3);       // TEAM_IDX[w]

    int base = offs[n];
    int dn = deg[n];
    int head = lane >> 4, egrp = lane & 15;
    int c0 = lane * 8;

    // per-lane weight block: 8 output channels x 5 inputs (160B contiguous)
    float wreg[40];
    const float4* wp = (const float4*)(W + c0 * IN_DIM);
#pragma unroll
    for (int i = 0; i < 10; i++) ((float4*)wreg)[i] = wp[i];

    float acc[8];
#pragma unroll
    for (int j = 0; j < 8; j++) acc[j] = -INFINITY;

    if (dn <= 16) {
        // single-pass softmax: lane egrp owns edge egrp for head (lane>>4)
        int slot = (egrp < dn) ? egrp : (dn - 1);
        int s_e = csr[base + slot];
        float adn = a_dst[n * HEADS + head];
        float tl = a_src[s_e * HEADS + head] + adn;
        tl = (tl > 0.f) ? tl : NEG_SLOPE * tl;
        if (egrp >= dn) tl = -INFINITY;
        float m = tl;
#pragma unroll
        for (int off = 8; off >= 1; off >>= 1) m = fmaxf(m, __shfl_xor(m, off));
        float ex = (egrp < dn) ? __expf(tl - m) : 0.f;
        float den = ex;
#pragma unroll
        for (int off = 8; off >= 1; off >>= 1) den += __shfl_xor(den, off);
        float attn = ex / den;

        for (int e = 0; e < dn; e++) {
            int s = __shfl(s_e, e);
            float a = __shfl(attn, (head << 4) | e);
            const float* xp = x + s * IN_DIM;   // broadcast: same addr all lanes
            float x0 = xp[0], x1 = xp[1], x2 = xp[2], x3 = xp[3], x4 = xp[4];
#pragma unroll
            for (int j = 0; j < 8; j++) {
                float hv = x0 * wreg[j * 5 + 0] + x1 * wreg[j * 5 + 1]
                         + x2 * wreg[j * 5 + 2] + x3 * wreg[j * 5 + 3]
                         + x4 * wreg[j * 5 + 4];
                acc[j] = fmaxf(acc[j], hv * a);
            }
        }
    } else {
        // fallback: 3-pass (rare, dn>16)
        float adn = a_dst[n * HEADS + head];
        float m = -INFINITY;
        for (int e0 = 0; e0 < dn; e0 += 16) {
            int e = e0 + egrp;
            if (e < dn) {
                int s = csr[base + e];
                float t = a_src[s * HEADS + head] + adn;
                t = (t > 0.f) ? t : NEG_SLOPE * t;
                m = fmaxf(m, t);
            }
        }
#pragma unroll
        for (int off = 8; off >= 1; off >>= 1) m = fmaxf(m, __shfl_xor(m, off));
        float den = 0.f;
        for (int e0 = 0; e0 < dn; e0 += 16) {
            int e = e0 + egrp;
            if (e < dn) {
                int s = csr[base + e];
                float t = a_src[s * HEADS + head] + adn;
                t = (t > 0.f) ? t : NEG_SLOPE * t;
                den += __expf(t - m);
            }
        }
#pragma unroll
        for (int off = 8; off >= 1; off >>= 1) den += __shfl_xor(den, off);
        float invden = 1.0f / den;
        for (int e = 0; e < dn; e++) {
            int s = csr[base + e];
            float t = a_src[s * HEADS + head] + adn;
            t = (t > 0.f) ? t : NEG_SLOPE * t;
            float attn = __expf(t - m) * invden;
            const float* xp = x + s * IN_DIM;
            float x0 = xp[0], x1 = xp[1], x2 = xp[2], x3 = xp[3], x4 = xp[4];
#pragma unroll
            for (int j = 0; j < 8; j++) {
                float hv = x0 * wreg[j * 5 + 0] + x1 * wreg[j * 5 + 1]
                         + x2 * wreg[j * 5 + 2] + x3 * wreg[j * 5 + 3]
                         + x4 * wreg[j * 5 + 4];
                acc[j] = fmaxf(acc[j], hv * attn);
            }
        }
    }

    bf16x8 ov;
#pragma unroll
    for (int j = 0; j < 8; j++) ov[j] = (short)f2bf(acc[j] + bias[c0 + j]);
    *(bf16x8*)(emb_sel + (size_t)w * HC + c0) = ov;
}

// ---------------------------------------------------------------------------
// bf16 MFMA GEMM — EXACT R9 config (best measured: 48us): 256x256 tile,
// BK=64, 512 threads (4m x 2n waves, 64x128/wave), LDK=72 pad, grid (2,98).
// A bf16; Wt fp32 converted in registers during staging.
// MODE 0: store relu(acc) bf16. MODE 1: fused final layer (dot W3, 16-lane
// shuffle reduce, f32 atomic partials — h2 never materialized).
// ---------------------------------------------------------------------------
#define BK  64
#define LDK 72

__device__ inline bf16x8 cvt8(float4 a, float4 b) {
    bf16x8 r;
    r[0] = (short)f2bf(a.x); r[1] = (short)f2bf(a.y);
    r[2] = (short)f2bf(a.z); r[3] = (short)f2bf(a.w);
    r[4] = (short)f2bf(b.x); r[5] = (short)f2bf(b.y);
    r[6] = (short)f2bf(b.z); r[7] = (short)f2bf(b.w);
    return r;
}

template <int MODE>
__global__ __launch_bounds__(512, 2) void k_gemm(const unsigned short* __restrict__ A, int M,
                                                 const float* __restrict__ Wt,
                                                 const float* __restrict__ bias,
                                                 unsigned short* __restrict__ C,
                                                 const float* __restrict__ W3,
                                                 float* __restrict__ part) {
    __shared__ unsigned short As[256 * LDK];
    __shared__ unsigned short Bs[256 * LDK];
    int tid = threadIdx.x;
    int m0 = blockIdx.y * 256;
    int o0 = blockIdx.x * 256;
    int wv = tid >> 6, lane = tid & 63;
    int wm = wv >> 1, wn = wv & 1;   // 4 x 2 wave grid

    f32x4 acc[4][8];
#pragma unroll
    for (int i = 0; i < 4; i++)
#pragma unroll
        for (int j = 0; j < 8; j++) acc[i][j] = (f32x4){0.f, 0.f, 0.f, 0.f};

    bf16x8 ra[4], rb[4];
#pragma unroll
    for (int s = 0; s < 4; s++) {
        int c = s * 512 + tid;           // 0..2047
        int row = c >> 3, col = (c & 7) * 8;
        int m = m0 + row;
        bf16x8 av = {0, 0, 0, 0, 0, 0, 0, 0};
        if (m < M) av = *(const bf16x8*)(A + (size_t)m * HC + col);
        ra[s] = av;
        const float4* wp = (const float4*)(Wt + (size_t)(o0 + row) * HC + col);
        rb[s] = cvt8(wp[0], wp[1]);
    }

    for (int k0 = 0; k0 < HC; k0 += BK) {
        __syncthreads();
#pragma unroll
        for (int s = 0; s < 4; s++) {
            int c = s * 512 + tid;
            int row = c >> 3, col = (c & 7) * 8;
            *(bf16x8*)(&As[row * LDK + col]) = ra[s];
            *(bf16x8*)(&Bs[row * LDK + col]) = rb[s];
        }
        __syncthreads();

        int kn = k0 + BK;
        if (kn < HC) {
#pragma unroll
            for (int s = 0; s < 4; s++) {
                int c = s * 512 + tid;
                int row = c >> 3, col = (c & 7) * 8;
                int m = m0 + row;
                bf16x8 av = {0, 0, 0, 0, 0, 0, 0, 0};
                if (m < M) av = *(const bf16x8*)(A + (size_t)m * HC + kn + col);
                ra[s] = av;
                const float4* wp = (const float4*)(Wt + (size_t)(o0 + row) * HC + kn + col);
                rb[s] = cvt8(wp[0], wp[1]);
            }
        }

#pragma unroll
        for (int kk = 0; kk < 2; kk++) {
            int kb = kk * 32 + (lane >> 4) * 8;
            bf16x8 af[4], bfr[8];
#pragma unroll
            for (int mi = 0; mi < 4; mi++)
                af[mi] = *(const bf16x8*)(&As[(wm * 64 + mi * 16 + (lane & 15)) * LDK + kb]);
#pragma unroll
            for (int ni = 0; ni < 8; ni++)
                bfr[ni] = *(const bf16x8*)(&Bs[(wn * 128 + ni * 16 + (lane & 15)) * LDK + kb]);
#pragma unroll
            for (int mi = 0; mi < 4; mi++)
#pragma unroll
                for (int ni = 0; ni < 8; ni++)
                    acc[mi][ni] = __builtin_amdgcn_mfma_f32_16x16x32_bf16(
                        af[mi], bfr[ni], acc[mi][ni], 0, 0, 0);
        }
    }

    if (MODE == 0) {
#pragma unroll
        for (int ni = 0; ni < 8; ni++) {
            int ncol = o0 + wn * 128 + ni * 16 + (lane & 15);
            float bv = bias[ncol];
#pragma unroll
            for (int mi = 0; mi < 4; mi++) {
                int mbase = m0 + wm * 64 + mi * 16 + (lane >> 4) * 4;
#pragma unroll
                for (int r = 0; r < 4; r++) {
                    int m = mbase + r;
                    if (m < M) {
                        float v = fmaxf(acc[mi][ni][r] + bv, 0.f);
                        C[(size_t)m * HC + ncol] = f2bf(v);
                    }
                }
            }
        }
    } else {
        float p0[4][4], p1[4][4];
#pragma unroll
        for (int mi = 0; mi < 4; mi++)
#pragma unroll
            for (int r = 0; r < 4; r++) { p0[mi][r] = 0.f; p1[mi][r] = 0.f; }
#pragma unroll
        for (int ni = 0; ni < 8; ni++) {
            int ncol = o0 + wn * 128 + ni * 16 + (lane & 15);
            float bv = bias[ncol];
            float w0 = W3[ncol], w1 = W3[HC + ncol];
#pragma unroll
            for (int mi = 0; mi < 4; mi++)
#pragma unroll
                for (int r = 0; r < 4; r++) {
                    float v = fmaxf(acc[mi][ni][r] + bv, 0.f);
                    p0[mi][r] += v * w0;
                    p1[mi][r] += v * w1;
                }
        }
#pragma unroll
        for (int mi = 0; mi < 4; mi++)
#pragma unroll
            for (int r = 0; r < 4; r++) {
                float a0 = p0[mi][r], a1 = p1[mi][r];
#pragma unroll
                for (int off = 8; off >= 1; off >>= 1) {
                    a0 += __shfl_xor(a0, off);
                    a1 += __shfl_xor(a1, off);
                }
                int m = m0 + wm * 64 + mi * 16 + (lane >> 4) * 4 + r;
                if ((lane & 15) == 0 && m < M) {
                    atomicAdd(&part[m * 2 + 0], a0);
                    atomicAdd(&part[m * 2 + 1], a1);
                }
            }
    }
}

// ---------------------------------------------------------------------------
// out[i] = tanh(part[i] + b3[i&1])
// ---------------------------------------------------------------------------
__global__ void k_tanh(const float* __restrict__ part, const float* __restrict__ b3,
                       float* __restrict__ out) {
    int i = blockIdx.x * 256 + threadIdx.x;
    if (i < 2 * M_SEL) out[i] = tanhf(part[i] + b3[i & 1]);
}

// ---------------------------------------------------------------------------
extern "C" void kernel_launch(void* const* d_in, const int* in_sizes, int n_in,
                              void* d_out, int out_size, void* d_ws, size_t ws_size,
                              hipStream_t stream) {
    const float* x       = (const float*)d_in[0];
    const int*   ei      = (const int*)d_in[1];
    const float* W       = (const float*)d_in[3];
    const float* att_src = (const float*)d_in[4];
    const float* att_dst = (const float*)d_in[5];
    const float* bias    = (const float*)d_in[6];
    const float* W1      = (const float*)d_in[7];
    const float* b1      = (const float*)d_in[8];
    const float* W2      = (const float*)d_in[9];
    const float* b2      = (const float*)d_in[10];
    const float* W3      = (const float*)d_in[11];
    const float* b3      = (const float*)d_in[12];
    float* out = (float*)d_out;

    char* ws = (char*)d_ws;
    unsigned short* emb_sel = (unsigned short*)(ws);               // 25,600,000
    unsigned short* h1      = (unsigned short*)(ws + 25600000);    // 25,600,000 (+OOB slack)
    float* part  = (float*)(ws + 51400000);                        //    200,000
    float* a_src = (float*)(ws + 51600000);                        //    800,000
    float* a_dst = (float*)(ws + 52400000);                        //    800,000
    int*   deg   = (int*)  (ws + 53200000);                        //    200,000
    int*   offs  = (int*)  (ws + 53400000);                        //    200,000
    int*   curs  = (int*)  (ws + 53600000);                        //    200,000
    int*   excl  = (int*)  (ws + 53800000);                        //    200,000
    int*   bsum  = (int*)  (ws + 54000000);                        //      1,024
    int*   csr   = (int*)  (ws + 54001024);                        //  1,800,000  (~56 MB)

    hipMemsetAsync(part, 0, 2 * M_SEL * sizeof(float), stream);
    k_transform<<<(N_NODES + 31) / 32, 256, 0, stream>>>(x, W, att_src, att_dst,
                                                         a_src, a_dst, deg);
    k_hist<<<(N_EDGES + 255) / 256, 256, 0, stream>>>(ei, deg);
    k_scan1<<<NSCAN_BLK, 256, 0, stream>>>(deg, excl, bsum);
    k_scan3fill<<<NSCAN_BLK, 256, 0, stream>>>(excl, bsum, offs, curs, csr);
    k_fill_edges<<<(N_EDGES + 255) / 256, 256, 0, stream>>>(ei, curs, csr);
    k_aggregate<<<6250, 256, 0, stream>>>(x, W, a_src, a_dst, csr, offs, deg, bias, emb_sel);

    dim3 g(2, 98);
    k_gemm<0><<<g, 512, 0, stream>>>(emb_sel, M_SEL, W1, b1, h1, nullptr, nullptr);
    k_gemm<1><<<g, 512, 0, stream>>>(h1, M_SEL, W2, b2, nullptr, W3, part);
    k_tanh<<<196, 256, 0, stream>>>(part, b3, out);
}